// Round 10
// baseline (77.797 us; speedup 1.0000x reference)
//
#include <hip/hip_runtime.h>
#include <math.h>

// Problem constants
#define BB   4
#define CIN  64
#define HH   64
#define WW   256
#define CO   128
#define NPIX (BB*HH*WW)       // 65536

typedef float  f32x4 __attribute__((ext_vector_type(4)));
typedef unsigned int u32x4 __attribute__((ext_vector_type(4)));
typedef _Float16 f16x8 __attribute__((ext_vector_type(8)));
typedef _Float16 f16x2 __attribute__((ext_vector_type(2)));

// Workspace layout (float/u32 slots). Total ~15.7 MB.
#define XTB_OFF  0
#define XTB_SZ   (NPIX*32)            // 2097152 u32: f16 x as [b][y][x][c], 2ch/u32
#define TAP_OFF  (XTB_OFF + XTB_SZ)
#define TAP_SZ   (27*NPIX)            // planes: dy[9], dx[9], mask[9] (f32)
#define OWB_OFF  (TAP_OFF + TAP_SZ)
#define OWB_SZ   9216                 // 18432 f16: offconv A-fragments [18][2][64][8]
#define WTF_OFF  (OWB_OFF + OWB_SZ)   // f16[9][8][2][64][8]: main A-frags, lane-linear

// XCD-aware block swizzle: 1024 = 8 XCDs x 128. Same mapping for transpose/
// offconv/main so producer and consumer of a row share an XCD L2.
__device__ inline int xcd_swz(int bid) { return (bid & 7) * 128 + (bid >> 3); }

// ---------------------------------------------------------------------------
// K0x: x [B][C][H][W] f32 -> xtb [B][H][W][C] f16 (packed 2ch/u32, linear order)
__global__ __launch_bounds__(256) void k_transpose_x(const float* __restrict__ x,
                                                     unsigned int* __restrict__ xtb) {
    __shared__ float t[64][65];
    int bx = xcd_swz(blockIdx.x);  // 1024 blocks: (b, y, xtile)
    int x0 = (bx & 3) * 64;
    int y  = (bx >> 2) & 63;
    int b  = bx >> 8;
    int tid = threadIdx.x;
    int lx = tid & 63, gy = tid >> 6;
#pragma unroll
    for (int i = 0; i < 16; ++i) {
        int c = i * 4 + gy;
        t[c][lx] = x[((b*CIN + c)*HH + y)*WW + x0 + lx];
    }
    __syncthreads();
    int px = tid & 63, cg = tid >> 6;      // 16 channels per cg
    u32x4 r0, r1;
#pragma unroll
    for (int j = 0; j < 4; ++j) {
        f16x2 p, q;
        p[0] = (_Float16)t[cg*16 + 2*j][px];
        p[1] = (_Float16)t[cg*16 + 2*j + 1][px];
        q[0] = (_Float16)t[cg*16 + 8 + 2*j][px];
        q[1] = (_Float16)t[cg*16 + 8 + 2*j + 1][px];
        r0[j] = __builtin_bit_cast(unsigned int, p);
        r1[j] = __builtin_bit_cast(unsigned int, q);
    }
    u32x4* dst = (u32x4*)(xtb + (((b*HH + y)*WW) + x0 + px)*32 + cg*8);
    dst[0] = r0; dst[1] = r1;
}

// ---------------------------------------------------------------------------
// K0w: weight prep (f16).
//  owb: offconv A-fragments (unchanged layout).
//  wtF: main-conv A-fragments, LANE-LINEAR: u32x4 index ((k*8+mi)*2+half)*64+l
//       holds W[oc=mi*16+(l&15)][c=half*32+(l>>4)*8+j] for tap k. Lane l reads
//       base+l*16B -> perfectly coalesced; same data for every wave -> L1-hot.
__global__ __launch_bounds__(256) void k_prep_w(const float* __restrict__ ow,
                                                const float* __restrict__ wm,
                                                unsigned short* __restrict__ owb,
                                                unsigned short* __restrict__ wtF) {
    const int n1 = 18432;
    const int n2 = 9*CO*CIN;   // 73728
    for (int i = blockIdx.x*blockDim.x + threadIdx.x;
         i < n1 + n2; i += gridDim.x*blockDim.x) {
        if (i < n1) {
            int j = i & 7, l = (i >> 3) & 63, mi = (i >> 9) & 1, kk = i >> 10;
            int oc = mi*16 + (l & 15);
            int k  = kk*32 + (l >> 4)*8 + j;
            int t = k >> 6, c = k & 63;
            float v = (oc < 27) ? ow[(oc*CIN + c)*9 + t] : 0.f;
            owb[i] = __builtin_bit_cast(unsigned short, (_Float16)v);
        } else {
            int j = i - n1;
            int jj = j & 7;
            int l  = (j >> 3) & 63;
            int half = (j >> 9) & 1;
            int mi = (j >> 10) & 7;
            int k  = j >> 13;                    // tap 0..8
            int oc = mi*16 + (l & 15);
            int c  = half*32 + (l >> 4)*8 + jj;
            float v = wm[(oc*CIN + c)*9 + k];
            wtF[j] = __builtin_bit_cast(unsigned short, (_Float16)v);
        }
    }
}

// ---------------------------------------------------------------------------
// K1: offset conv via f16 MFMA. 1024 blocks x 4 waves; wave = 32(oc) x 16(px).
__global__ __launch_bounds__(256) void k_offconv(const unsigned int* __restrict__ xtb,
                                                 const unsigned short* __restrict__ owb,
                                                 const float* __restrict__ ob,
                                                 float* __restrict__ tap) {
    __shared__ u32x4 awl[2304];        // 36864 B
    int bx = xcd_swz(blockIdx.x);      // 1024: (b, ho, wtile)
    int wtile = bx & 3, ho = (bx >> 2) & 63, b = bx >> 8;
    int tid = threadIdx.x;
    {
        const u32x4* asrc = (const u32x4*)owb;
#pragma unroll
        for (int i = 0; i < 9; ++i) awl[tid + i*256] = asrc[tid + i*256];
    }
    __syncthreads();
    int w = tid >> 6, l = tid & 63;
    int pxl = l & 15, hi = l >> 4;
    int wo = wtile*64 + w*16 + pxl;

    f32x4 acc0 = (f32x4){0.f,0.f,0.f,0.f}, acc1 = (f32x4){0.f,0.f,0.f,0.f};
#pragma unroll
    for (int kk = 0; kk < 18; ++kk) {
        const int t = kk >> 1;
        const int ki = t / 3, kj = t % 3;
        int y  = ho + ki - 1;
        int xx = wo + kj - 1;
        bool v = (y >= 0) && (y < HH) && (xx >= 0) && (xx < WW);
        int yc = min(max(y, 0), HH-1), xc = min(max(xx, 0), WW-1);
        const u32x4* p = (const u32x4*)(xtb + ((b*HH + yc)*WW + xc)*32);
        u32x4 bv = p[(kk & 1)*4 + hi];
        if (!v) bv = (u32x4){0u,0u,0u,0u};
        u32x4 a0 = awl[(kk*2+0)*64 + l];
        u32x4 a1 = awl[(kk*2+1)*64 + l];
        acc0 = __builtin_amdgcn_mfma_f32_16x16x32_f16(
                   __builtin_bit_cast(f16x8, a0), __builtin_bit_cast(f16x8, bv), acc0, 0, 0, 0);
        acc1 = __builtin_amdgcn_mfma_f32_16x16x32_f16(
                   __builtin_bit_cast(f16x8, a1), __builtin_bit_cast(f16x8, bv), acc1, 0, 0, 0);
    }

    int gpix = (b*HH + ho)*WW + wo;
#pragma unroll
    for (int r = 0; r < 4; ++r) {
        int oc0 = hi*4 + r;                       // 0..15: dy/dx planes
        float v0 = acc0[r] + ob[oc0];
        int plane0 = (oc0 & 1)*9 + (oc0 >> 1);
        tap[plane0*NPIX + gpix] = v0;
        int oc1 = 16 + hi*4 + r;                  // 16..31
        if (oc1 < 27) {
            float v1 = acc1[r] + ob[oc1];
            float vv; int plane1;
            if (oc1 < 18) { plane1 = (oc1 & 1)*9 + (oc1 >> 1); vv = v1; }
            else { plane1 = oc1; vv = 1.f / (1.f + __expf(-v1)); }
            tap[plane1*NPIX + gpix] = vv;
        }
    }
}

// ---------------------------------------------------------------------------
// packed-f16 bilinear lerp: r = a*w0 + b*w1 + c*w2 + d*w3 (v_pk_fma_f16)
__device__ inline f16x8 lerp8h(u32x4 a, u32x4 b, u32x4 c, u32x4 d,
                               f16x8 w0, f16x8 w1, f16x8 w2, f16x8 w3) {
    f16x8 av = __builtin_bit_cast(f16x8, a);
    f16x8 bv = __builtin_bit_cast(f16x8, b);
    f16x8 cv = __builtin_bit_cast(f16x8, c);
    f16x8 dv = __builtin_bit_cast(f16x8, d);
    return av*w0 + bv*w1 + cv*w2 + dv*w3;
}

__device__ inline f16x8 splat8(float s) {
    _Float16 h = (_Float16)s;
    return (f16x8){h, h, h, h, h, h, h, h};
}

// ---------------------------------------------------------------------------
// K2: fused deformable sampling + f16 MFMA GEMM. NO LDS, NO BARRIERS.
// Wave = 128(o) x 16(px), fully independent. A-fragments read straight from
// global in lane-linear order (L1-hot, coalesced); gathers pipelined 1 tap ahead.
__global__ __launch_bounds__(256) void k_main(const unsigned int* __restrict__ xtb,
                                              const float* __restrict__ tap,
                                              const unsigned short* __restrict__ wtF,
                                              float* __restrict__ out) {
    int bx = xcd_swz(blockIdx.x);
    int wtile = bx & 3, ho = (bx >> 2) & 63, b = bx >> 8;
    int tid = threadIdx.x;
    int w = tid >> 6;
    int l = tid & 63;
    int pxl = l & 15, hi = l >> 4;
    int wo = wtile*64 + w*16 + pxl;
    int gpix = (b*HH + ho)*WW + wo;

    // hoist all tap params (27 independent loads, one latency)
    float tdy[9], tdx[9], tm[9];
#pragma unroll
    for (int k = 0; k < 9; ++k) {
        tdy[k] = tap[k*NPIX + gpix];
        tdx[k] = tap[(9+k)*NPIX + gpix];
        tm[k]  = tap[(18+k)*NPIX + gpix];
    }

    // compute addresses + issue the 8 gathers + lerp weights for tap k
    auto issue_tap = [&](int k, u32x4* G, float* W) {
        float dy = tdy[k], dx = tdx[k], m = tm[k];
        int ki = k / 3, kj = k - ki*3;
        float py  = dy + (float)(ho - 1 + ki);
        float pxf = dx + (float)(wo - 1 + kj);
        float y0f = floorf(py), x0f = floorf(pxf);
        float ly = py - y0f, lxf = pxf - x0f;
        int y0 = (int)y0f, x0 = (int)x0f;
        int y1 = y0 + 1,  x1 = x0 + 1;
        bool vy0 = (y0 >= 0) && (y0 < HH), vy1 = (y1 >= 0) && (y1 < HH);
        bool vx0 = (x0 >= 0) && (x0 < WW), vx1 = (x1 >= 0) && (x1 < WW);
        float hy = 1.f - ly, hx = 1.f - lxf;
        W[0] = (vy0 && vx0) ? hy*hx*m : 0.f;
        W[1] = (vy0 && vx1) ? hy*lxf*m : 0.f;
        W[2] = (vy1 && vx0) ? ly*hx*m : 0.f;
        W[3] = (vy1 && vx1) ? ly*lxf*m : 0.f;
        int yc0 = min(max(y0, 0), HH-1), yc1 = min(max(y1, 0), HH-1);
        int xc0 = min(max(x0, 0), WW-1), xc1 = min(max(x1, 0), WW-1);
        const u32x4* p00 = (const u32x4*)(xtb + ((b*HH + yc0)*WW + xc0)*32);
        const u32x4* p01 = (const u32x4*)(xtb + ((b*HH + yc0)*WW + xc1)*32);
        const u32x4* p10 = (const u32x4*)(xtb + ((b*HH + yc1)*WW + xc0)*32);
        const u32x4* p11 = (const u32x4*)(xtb + ((b*HH + yc1)*WW + xc1)*32);
        G[0] = p00[hi];   G[1] = p01[hi];   G[2] = p10[hi];   G[3] = p11[hi];
        G[4] = p00[hi+4]; G[5] = p01[hi+4]; G[6] = p10[hi+4]; G[7] = p11[hi+4];
    };

    const u32x4* asrc = (const u32x4*)wtF;   // ((k*8+mi)*2+half)*64 + l

    f32x4 acc[8];
#pragma unroll
    for (int i = 0; i < 8; ++i) acc[i] = (f32x4){0.f, 0.f, 0.f, 0.f};

    u32x4 GA[8], GB[8];
    float WA[4], WB[4];
    issue_tap(0, GA, WA);

#pragma unroll
    for (int k = 0; k < 9; ++k) {
        u32x4 *G, *Gn; float *W, *Wn;
        if (k & 1) { G = GB; W = WB; Gn = GA; Wn = WA; }
        else       { G = GA; W = WA; Gn = GB; Wn = WB; }

        // issue next tap's gathers (latency hides under this tap's lerp+MFMA)
        if (k < 8) issue_tap(k+1, Gn, Wn);

        // ---- lerp tap k -> B fragments (packed f16 math)
        f16x8 w0v = splat8(W[0]), w1v = splat8(W[1]), w2v = splat8(W[2]), w3v = splat8(W[3]);
        f16x8 bf0 = lerp8h(G[0], G[1], G[2], G[3], w0v, w1v, w2v, w3v);
        f16x8 bf1 = lerp8h(G[4], G[5], G[6], G[7], w0v, w1v, w2v, w3v);

        // ---- MFMA, A-fragments streamed from global (coalesced, L1-hot)
        const u32x4* ak = asrc + (k*16)*64 + l;
#pragma unroll
        for (int mi = 0; mi < 8; ++mi) {
            u32x4 a0 = ak[(mi*2 + 0)*64];
            u32x4 a1 = ak[(mi*2 + 1)*64];
            acc[mi] = __builtin_amdgcn_mfma_f32_16x16x32_f16(
                          __builtin_bit_cast(f16x8, a0), bf0, acc[mi], 0, 0, 0);
            acc[mi] = __builtin_amdgcn_mfma_f32_16x16x32_f16(
                          __builtin_bit_cast(f16x8, a1), bf1, acc[mi], 0, 0, 0);
        }
    }

#pragma unroll
    for (int mi = 0; mi < 8; ++mi) {
#pragma unroll
        for (int r = 0; r < 4; ++r) {
            int o = mi*16 + hi*4 + r;     // C/D: col=lane&15(px), row=(lane>>4)*4+reg
            out[((b*CO + o)*HH + ho)*WW + wo] = acc[mi][r];
        }
    }
}

// ---------------------------------------------------------------------------
extern "C" void kernel_launch(void* const* d_in, const int* in_sizes, int n_in,
                              void* d_out, int out_size, void* d_ws, size_t ws_size,
                              hipStream_t stream) {
    const float* x  = (const float*)d_in[0];
    const float* ow = (const float*)d_in[1];
    const float* ob = (const float*)d_in[2];
    const float* wm = (const float*)d_in[3];
    float* outp = (float*)d_out;

    float* ws   = (float*)d_ws;
    unsigned int* xtb = (unsigned int*)(ws + XTB_OFF);
    float* tap  = ws + TAP_OFF;
    unsigned short* owb = (unsigned short*)(ws + OWB_OFF);
    unsigned short* wtF = (unsigned short*)(ws + WTF_OFF);

    k_transpose_x<<<1024, 256, 0, stream>>>(x, xtb);
    k_prep_w<<<360, 256, 0, stream>>>(ow, wm, owb, wtF);
    k_offconv<<<1024, 256, 0, stream>>>(xtb, owb, ob, tap);
    k_main<<<1024, 256, 0, stream>>>(xtb, tap, wtF, outp);
}

// Round 11
// 70.723 us; speedup vs baseline: 1.1000x; 1.1000x over previous
//
#include <hip/hip_runtime.h>
#include <math.h>

// Problem constants
#define BB   4
#define CIN  64
#define HH   64
#define WW   256
#define CO   128
#define NPIX (BB*HH*WW)       // 65536

typedef float  f32x4 __attribute__((ext_vector_type(4)));
typedef unsigned int u32x4 __attribute__((ext_vector_type(4)));
typedef _Float16 f16x8 __attribute__((ext_vector_type(8)));
typedef _Float16 f16x2 __attribute__((ext_vector_type(2)));

// Workspace layout (float/u32 slots). Total ~15.7 MB.
#define XTB_OFF  0
#define XTB_SZ   (NPIX*32)            // 2097152 u32: f16 x as [b][y][x][c], 2ch/u32
#define TAP_OFF  (XTB_OFF + XTB_SZ)
#define TAP_SZ   (27*NPIX)            // planes: dy[9], dx[9], mask[9] (f32)
#define OWB_OFF  (TAP_OFF + TAP_SZ)
#define OWB_SZ   9216                 // 18432 f16: offconv A-fragments [18][2][64][8]
#define WTF_OFF  (OWB_OFF + OWB_SZ)   // ushort[9][8192] f16 A-frag, XOR-swizzled

// XCD-aware block swizzle: 1024 = 8 XCDs x 128. Same mapping for transpose/
// offconv/main so producer and consumer of a row share an XCD L2.
__device__ inline int xcd_swz(int bid) { return (bid & 7) * 128 + (bid >> 3); }

// ---------------------------------------------------------------------------
// K0x: x [B][C][H][W] f32 -> xtb [B][H][W][C] f16 (packed 2ch/u32, linear order)
__global__ __launch_bounds__(256) void k_transpose_x(const float* __restrict__ x,
                                                     unsigned int* __restrict__ xtb) {
    __shared__ float t[64][65];
    int bx = xcd_swz(blockIdx.x);  // 1024 blocks: (b, y, xtile)
    int x0 = (bx & 3) * 64;
    int y  = (bx >> 2) & 63;
    int b  = bx >> 8;
    int tid = threadIdx.x;
    int lx = tid & 63, gy = tid >> 6;
#pragma unroll
    for (int i = 0; i < 16; ++i) {
        int c = i * 4 + gy;
        t[c][lx] = x[((b*CIN + c)*HH + y)*WW + x0 + lx];
    }
    __syncthreads();
    int px = tid & 63, cg = tid >> 6;      // 16 channels per cg
    u32x4 r0, r1;
#pragma unroll
    for (int j = 0; j < 4; ++j) {
        f16x2 p, q;
        p[0] = (_Float16)t[cg*16 + 2*j][px];
        p[1] = (_Float16)t[cg*16 + 2*j + 1][px];
        q[0] = (_Float16)t[cg*16 + 8 + 2*j][px];
        q[1] = (_Float16)t[cg*16 + 8 + 2*j + 1][px];
        r0[j] = __builtin_bit_cast(unsigned int, p);
        r1[j] = __builtin_bit_cast(unsigned int, q);
    }
    u32x4* dst = (u32x4*)(xtb + (((b*HH + y)*WW) + x0 + px)*32 + cg*8);
    dst[0] = r0; dst[1] = r1;
}

// ---------------------------------------------------------------------------
// K0w: weight prep (f16).
//  owb: offconv A-fragments.
//  wtF [k][ (o*64+c) ^ ((o&7)<<3) ]: f16, A-fragment rows pre-swizzled
__global__ __launch_bounds__(256) void k_prep_w(const float* __restrict__ ow,
                                                const float* __restrict__ wm,
                                                unsigned short* __restrict__ owb,
                                                unsigned short* __restrict__ wtF) {
    const int n1 = 18432;
    const int n2 = 9*CO*CIN;
    for (int i = blockIdx.x*blockDim.x + threadIdx.x;
         i < n1 + n2; i += gridDim.x*blockDim.x) {
        if (i < n1) {
            int j = i & 7, l = (i >> 3) & 63, mi = (i >> 9) & 1, kk = i >> 10;
            int oc = mi*16 + (l & 15);
            int k  = kk*32 + (l >> 4)*8 + j;
            int t = k >> 6, c = k & 63;
            float v = (oc < 27) ? ow[(oc*CIN + c)*9 + t] : 0.f;
            owb[i] = __builtin_bit_cast(unsigned short, (_Float16)v);
        } else {
            int j = i - n1;
            int k = j / (CO*CIN);
            int r = j % (CO*CIN);      // r = o*64 + c
            int o = r / CIN, c = r % CIN;
            float v = wm[(o*CIN + c)*9 + k];
            wtF[k*8192 + (r ^ ((o & 7) << 3))] =
                __builtin_bit_cast(unsigned short, (_Float16)v);
        }
    }
}

// ---------------------------------------------------------------------------
// K1: offset conv via f16 MFMA. 1024 blocks x 4 waves; wave = 32(oc) x 16(px).
__global__ __launch_bounds__(256) void k_offconv(const unsigned int* __restrict__ xtb,
                                                 const unsigned short* __restrict__ owb,
                                                 const float* __restrict__ ob,
                                                 float* __restrict__ tap) {
    __shared__ u32x4 awl[2304];        // 36864 B
    int bx = xcd_swz(blockIdx.x);      // 1024: (b, ho, wtile)
    int wtile = bx & 3, ho = (bx >> 2) & 63, b = bx >> 8;
    int tid = threadIdx.x;
    {
        const u32x4* asrc = (const u32x4*)owb;
#pragma unroll
        for (int i = 0; i < 9; ++i) awl[tid + i*256] = asrc[tid + i*256];
    }
    __syncthreads();
    int w = tid >> 6, l = tid & 63;
    int pxl = l & 15, hi = l >> 4;
    int wo = wtile*64 + w*16 + pxl;

    f32x4 acc0 = (f32x4){0.f,0.f,0.f,0.f}, acc1 = (f32x4){0.f,0.f,0.f,0.f};
#pragma unroll
    for (int kk = 0; kk < 18; ++kk) {
        const int t = kk >> 1;
        const int ki = t / 3, kj = t % 3;
        int y  = ho + ki - 1;
        int xx = wo + kj - 1;
        bool v = (y >= 0) && (y < HH) && (xx >= 0) && (xx < WW);
        int yc = min(max(y, 0), HH-1), xc = min(max(xx, 0), WW-1);
        const u32x4* p = (const u32x4*)(xtb + ((b*HH + yc)*WW + xc)*32);
        u32x4 bv = p[(kk & 1)*4 + hi];
        if (!v) bv = (u32x4){0u,0u,0u,0u};
        u32x4 a0 = awl[(kk*2+0)*64 + l];
        u32x4 a1 = awl[(kk*2+1)*64 + l];
        acc0 = __builtin_amdgcn_mfma_f32_16x16x32_f16(
                   __builtin_bit_cast(f16x8, a0), __builtin_bit_cast(f16x8, bv), acc0, 0, 0, 0);
        acc1 = __builtin_amdgcn_mfma_f32_16x16x32_f16(
                   __builtin_bit_cast(f16x8, a1), __builtin_bit_cast(f16x8, bv), acc1, 0, 0, 0);
    }

    int gpix = (b*HH + ho)*WW + wo;
#pragma unroll
    for (int r = 0; r < 4; ++r) {
        int oc0 = hi*4 + r;                       // 0..15: dy/dx planes
        float v0 = acc0[r] + ob[oc0];
        int plane0 = (oc0 & 1)*9 + (oc0 >> 1);
        tap[plane0*NPIX + gpix] = v0;
        int oc1 = 16 + hi*4 + r;                  // 16..31
        if (oc1 < 27) {
            float v1 = acc1[r] + ob[oc1];
            float vv; int plane1;
            if (oc1 < 18) { plane1 = (oc1 & 1)*9 + (oc1 >> 1); vv = v1; }
            else { plane1 = oc1; vv = 1.f / (1.f + __expf(-v1)); }
            tap[plane1*NPIX + gpix] = vv;
        }
    }
}

// ---------------------------------------------------------------------------
// packed-f16 bilinear lerp of one 8-channel chunk
__device__ inline f16x8 lerp8h(u32x4 a, u32x4 b, u32x4 c, u32x4 d,
                               f16x8 w0, f16x8 w1, f16x8 w2, f16x8 w3) {
    f16x8 av = __builtin_bit_cast(f16x8, a);
    f16x8 bv = __builtin_bit_cast(f16x8, b);
    f16x8 cv = __builtin_bit_cast(f16x8, c);
    f16x8 dv = __builtin_bit_cast(f16x8, d);
    return av*w0 + bv*w1 + cv*w2 + dv*w3;
}

__device__ inline f16x8 splat8(float s) {
    _Float16 h = (_Float16)s;
    return (f16x8){h, h, h, h, h, h, h, h};
}

// ---------------------------------------------------------------------------
// K2: fused deformable sampling + f16 MFMA GEMM, K-SPLIT.
// 1024 blocks x 8 waves. Wave = 128(oc) x 16(px) x 32(ch half). half=w&1 picks
// channels half*32..+31: per wave/tap only 4 gathers, 8 ds_read, 8 MFMA.
// Cross-half f32 reduction through LDS at the end. Weights: LDS double-buffer
// (2x16KB) with lgkm-only barrier; gathers + params pipelined ahead.
__global__ __launch_bounds__(512) void k_main(const unsigned int* __restrict__ xtb,
                                              const float* __restrict__ tap,
                                              const unsigned short* __restrict__ wtF,
                                              float* __restrict__ out) {
    __shared__ u32x4 wlds[2048];   // 32 KB: two 16KB buffers; reused for reduction
    int bx = xcd_swz(blockIdx.x);
    int wtile = bx & 3, ho = (bx >> 2) & 63, b = bx >> 8;
    int tid = threadIdx.x;
    int w = tid >> 6;
    int half = w & 1;              // K-half
    int pg = w >> 1;               // pixel group 0..3
    int l = tid & 63;
    int pxl = l & 15, hi = l >> 4;
    int wo = wtile*64 + pg*16 + pxl;
    int gpix = (b*HH + ho)*WW + wo;

    // A-fragment swizzled byte offset (within a 16KB buffer): row=oc(l&15),
    // cols = half*32 + hi*8 .. +8
    int loA = (half*64 + hi*16) ^ ((l & 7) << 4);
    int abase = pxl * 128;
    const int chunk = half*4 + hi;   // xtb u32x4 chunk holding this lane's 8 ch

    // issue gathers + lerp weights for tap k (params passed in)
    auto issue_tap = [&](int k, u32x4* G, float* W, float dy, float dx, float m) {
        int ki = k / 3, kj = k - ki*3;
        float py  = dy + (float)(ho - 1 + ki);
        float pxf = dx + (float)(wo - 1 + kj);
        float y0f = floorf(py), x0f = floorf(pxf);
        float ly = py - y0f, lxf = pxf - x0f;
        int y0 = (int)y0f, x0 = (int)x0f;
        int y1 = y0 + 1,  x1 = x0 + 1;
        bool vy0 = (y0 >= 0) && (y0 < HH), vy1 = (y1 >= 0) && (y1 < HH);
        bool vx0 = (x0 >= 0) && (x0 < WW), vx1 = (x1 >= 0) && (x1 < WW);
        float hy = 1.f - ly, hx = 1.f - lxf;
        W[0] = (vy0 && vx0) ? hy*hx*m : 0.f;
        W[1] = (vy0 && vx1) ? hy*lxf*m : 0.f;
        W[2] = (vy1 && vx0) ? ly*hx*m : 0.f;
        W[3] = (vy1 && vx1) ? ly*lxf*m : 0.f;
        int yc0 = min(max(y0, 0), HH-1), yc1 = min(max(y1, 0), HH-1);
        int xc0 = min(max(x0, 0), WW-1), xc1 = min(max(x1, 0), WW-1);
        const u32x4* p00 = (const u32x4*)(xtb + ((b*HH + yc0)*WW + xc0)*32);
        const u32x4* p01 = (const u32x4*)(xtb + ((b*HH + yc0)*WW + xc1)*32);
        const u32x4* p10 = (const u32x4*)(xtb + ((b*HH + yc1)*WW + xc0)*32);
        const u32x4* p11 = (const u32x4*)(xtb + ((b*HH + yc1)*WW + xc1)*32);
        G[0] = p00[chunk]; G[1] = p01[chunk]; G[2] = p10[chunk]; G[3] = p11[chunk];
    };

    const u32x4* wsrc = (const u32x4*)wtF;
    {   // stage tap 0 weights into buffer 0
        u32x4 s0 = wsrc[tid], s1 = wsrc[tid+512];
        wlds[tid] = s0; wlds[tid+512] = s1;
    }

    f32x4 acc[8];
#pragma unroll
    for (int i = 0; i < 8; ++i) acc[i] = (f32x4){0.f, 0.f, 0.f, 0.f};

    // tap-param pipeline: cur = par(k+1) at iter k (loaded 1 tap ahead)
    float dy0 = tap[gpix], dx0 = tap[9*NPIX + gpix], m0 = tap[18*NPIX + gpix];
    float dyN = tap[NPIX + gpix], dxN = tap[10*NPIX + gpix], mN = tap[19*NPIX + gpix];

    u32x4 GA[4], GB[4];
    float WA[4], WB[4];
    issue_tap(0, GA, WA, dy0, dx0, m0);
    __syncthreads();

#pragma unroll
    for (int k = 0; k < 9; ++k) {
        u32x4 *G, *Gn; float *W, *Wn;
        if (k & 1) { G = GB; W = WB; Gn = GA; Wn = WA; }
        else       { G = GA; W = WA; Gn = GB; Wn = WB; }

        // issue next tap's staging loads + gathers; refill param pipeline
        u32x4 s0, s1;
        if (k < 8) {
            const u32x4* ws2 = wsrc + (k+1)*1024;
            s0 = ws2[tid]; s1 = ws2[tid+512];
            issue_tap(k+1, Gn, Wn, dyN, dxN, mN);
        }
        if (k < 7) {
            dyN = tap[(k+2)*NPIX + gpix];
            dxN = tap[(11+k)*NPIX + gpix];
            mN  = tap[(20+k)*NPIX + gpix];
        }

        // ---- lerp tap k -> this half's B fragment
        f16x8 bf = lerp8h(G[0], G[1], G[2], G[3],
                          splat8(W[0]), splat8(W[1]), splat8(W[2]), splat8(W[3]));

        // ---- 8 MFMA from current buffer
        const char* wb = (const char*)wlds + (k & 1)*16384;
#pragma unroll
        for (int mi = 0; mi < 8; ++mi) {
            u32x4 a = *(const u32x4*)(wb + (abase + loA + mi*2048));
            acc[mi] = __builtin_amdgcn_mfma_f32_16x16x32_f16(
                          __builtin_bit_cast(f16x8, a), bf, acc[mi], 0, 0, 0);
        }

        // ---- write next buffer; lgkm-only barrier (keep gathers in flight)
        if (k < 8) {
            u32x4* nb = wlds + ((k+1) & 1)*1024;
            nb[tid] = s0; nb[tid+512] = s1;
            asm volatile("s_waitcnt lgkmcnt(0)\n\ts_barrier" ::: "memory");
        }
    }

    // ---- cross-half reduction through LDS, then store (half 0 writes out)
    __syncthreads();                       // all MFMA reads of wlds done
    float* red = (float*)wlds;
    int rb = pg*2048 + l*32;
    if (half == 1) {
#pragma unroll
        for (int mi = 0; mi < 8; ++mi)
            *(f32x4*)&red[rb + ((mi ^ (l & 7)) << 2)] = acc[mi];
    }
    __syncthreads();
    if (half == 0) {
#pragma unroll
        for (int mi = 0; mi < 8; ++mi) {
            acc[mi] += *(const f32x4*)&red[rb + ((mi ^ (l & 7)) << 2)];
#pragma unroll
            for (int r = 0; r < 4; ++r) {
                int o = mi*16 + hi*4 + r;  // C/D: col=lane&15(px), row=hi*4+reg
                out[((b*CO + o)*HH + ho)*WW + wo] = acc[mi][r];
            }
        }
    }
}

// ---------------------------------------------------------------------------
extern "C" void kernel_launch(void* const* d_in, const int* in_sizes, int n_in,
                              void* d_out, int out_size, void* d_ws, size_t ws_size,
                              hipStream_t stream) {
    const float* x  = (const float*)d_in[0];
    const float* ow = (const float*)d_in[1];
    const float* ob = (const float*)d_in[2];
    const float* wm = (const float*)d_in[3];
    float* outp = (float*)d_out;

    float* ws   = (float*)d_ws;
    unsigned int* xtb = (unsigned int*)(ws + XTB_OFF);
    float* tap  = ws + TAP_OFF;
    unsigned short* owb = (unsigned short*)(ws + OWB_OFF);
    unsigned short* wtF = (unsigned short*)(ws + WTF_OFF);

    k_transpose_x<<<1024, 256, 0, stream>>>(x, xtb);
    k_prep_w<<<360, 256, 0, stream>>>(ow, wm, owb, wtF);
    k_offconv<<<1024, 256, 0, stream>>>(xtb, owb, ob, tap);
    k_main<<<1024, 512, 0, stream>>>(xtb, tap, wtF, outp);
}

// Round 12
// 65.029 us; speedup vs baseline: 1.1963x; 1.0876x over previous
//
#include <hip/hip_runtime.h>
#include <math.h>

// Problem constants
#define BB   4
#define CIN  64
#define HH   64
#define WW   256
#define CO   128
#define NPIX (BB*HH*WW)       // 65536

typedef float  f32x4 __attribute__((ext_vector_type(4)));
typedef unsigned int u32x4 __attribute__((ext_vector_type(4)));
typedef _Float16 f16x8 __attribute__((ext_vector_type(8)));
typedef _Float16 f16x2 __attribute__((ext_vector_type(2)));

// Workspace layout (float/u32 slots). Total ~15.7 MB.
#define XTB_OFF  0
#define XTB_SZ   (NPIX*32)            // 2097152 u32: f16 x as [b][y][x][c], 2ch/u32
#define TAP_OFF  (XTB_OFF + XTB_SZ)
#define TAP_SZ   (27*NPIX)            // planes: dy[9], dx[9], mask[9] (f32)
#define OWB_OFF  (TAP_OFF + TAP_SZ)
#define OWB_SZ   9216                 // 18432 f16: offconv A-fragments [18][2][64][8]
#define WTF_OFF  (OWB_OFF + OWB_SZ)   // ushort[9][8192] f16 A-frag, XOR-swizzled

// XCD-aware block swizzles (8 XCDs). Chunks chosen so the SAME image rows land
// on the same XCD across transpose(1024) / offconv(1024) / main(256).
__device__ inline int xcd_swz(int bid)    { return (bid & 7) * 128 + (bid >> 3); }
__device__ inline int xcd_swz256(int bid) { return (bid & 7) * 32  + (bid >> 3); }

// ---------------------------------------------------------------------------
// K0x: x [B][C][H][W] f32 -> xtb [B][H][W][C] f16 (packed 2ch/u32, linear order)
__global__ __launch_bounds__(256) void k_transpose_x(const float* __restrict__ x,
                                                     unsigned int* __restrict__ xtb) {
    __shared__ float t[64][65];
    int bx = xcd_swz(blockIdx.x);  // 1024 blocks: (b, y, xtile)
    int x0 = (bx & 3) * 64;
    int y  = (bx >> 2) & 63;
    int b  = bx >> 8;
    int tid = threadIdx.x;
    int lx = tid & 63, gy = tid >> 6;
#pragma unroll
    for (int i = 0; i < 16; ++i) {
        int c = i * 4 + gy;
        t[c][lx] = x[((b*CIN + c)*HH + y)*WW + x0 + lx];
    }
    __syncthreads();
    int px = tid & 63, cg = tid >> 6;      // 16 channels per cg
    u32x4 r0, r1;
#pragma unroll
    for (int j = 0; j < 4; ++j) {
        f16x2 p, q;
        p[0] = (_Float16)t[cg*16 + 2*j][px];
        p[1] = (_Float16)t[cg*16 + 2*j + 1][px];
        q[0] = (_Float16)t[cg*16 + 8 + 2*j][px];
        q[1] = (_Float16)t[cg*16 + 8 + 2*j + 1][px];
        r0[j] = __builtin_bit_cast(unsigned int, p);
        r1[j] = __builtin_bit_cast(unsigned int, q);
    }
    u32x4* dst = (u32x4*)(xtb + (((b*HH + y)*WW) + x0 + px)*32 + cg*8);
    dst[0] = r0; dst[1] = r1;
}

// ---------------------------------------------------------------------------
// K0w: weight prep (f16).
//  owb: offconv A-fragments.
//  wtF [k][ (o*64+c) ^ ((o&7)<<3) ]: f16, A-fragment rows pre-swizzled
__global__ __launch_bounds__(256) void k_prep_w(const float* __restrict__ ow,
                                                const float* __restrict__ wm,
                                                unsigned short* __restrict__ owb,
                                                unsigned short* __restrict__ wtF) {
    const int n1 = 18432;
    const int n2 = 9*CO*CIN;
    for (int i = blockIdx.x*blockDim.x + threadIdx.x;
         i < n1 + n2; i += gridDim.x*blockDim.x) {
        if (i < n1) {
            int j = i & 7, l = (i >> 3) & 63, mi = (i >> 9) & 1, kk = i >> 10;
            int oc = mi*16 + (l & 15);
            int k  = kk*32 + (l >> 4)*8 + j;
            int t = k >> 6, c = k & 63;
            float v = (oc < 27) ? ow[(oc*CIN + c)*9 + t] : 0.f;
            owb[i] = __builtin_bit_cast(unsigned short, (_Float16)v);
        } else {
            int j = i - n1;
            int k = j / (CO*CIN);
            int r = j % (CO*CIN);      // r = o*64 + c
            int o = r / CIN, c = r % CIN;
            float v = wm[(o*CIN + c)*9 + k];
            wtF[k*8192 + (r ^ ((o & 7) << 3))] =
                __builtin_bit_cast(unsigned short, (_Float16)v);
        }
    }
}

// ---------------------------------------------------------------------------
// K1: offset conv via f16 MFMA. 1024 blocks x 4 waves; wave = 32(oc) x 16(px).
__global__ __launch_bounds__(256) void k_offconv(const unsigned int* __restrict__ xtb,
                                                 const unsigned short* __restrict__ owb,
                                                 const float* __restrict__ ob,
                                                 float* __restrict__ tap) {
    __shared__ u32x4 awl[2304];        // 36864 B
    int bx = xcd_swz(blockIdx.x);      // 1024: (b, ho, wtile)
    int wtile = bx & 3, ho = (bx >> 2) & 63, b = bx >> 8;
    int tid = threadIdx.x;
    {
        const u32x4* asrc = (const u32x4*)owb;
#pragma unroll
        for (int i = 0; i < 9; ++i) awl[tid + i*256] = asrc[tid + i*256];
    }
    __syncthreads();
    int w = tid >> 6, l = tid & 63;
    int pxl = l & 15, hi = l >> 4;
    int wo = wtile*64 + w*16 + pxl;

    f32x4 acc0 = (f32x4){0.f,0.f,0.f,0.f}, acc1 = (f32x4){0.f,0.f,0.f,0.f};
#pragma unroll
    for (int kk = 0; kk < 18; ++kk) {
        const int t = kk >> 1;
        const int ki = t / 3, kj = t % 3;
        int y  = ho + ki - 1;
        int xx = wo + kj - 1;
        bool v = (y >= 0) && (y < HH) && (xx >= 0) && (xx < WW);
        int yc = min(max(y, 0), HH-1), xc = min(max(xx, 0), WW-1);
        const u32x4* p = (const u32x4*)(xtb + ((b*HH + yc)*WW + xc)*32);
        u32x4 bv = p[(kk & 1)*4 + hi];
        if (!v) bv = (u32x4){0u,0u,0u,0u};
        u32x4 a0 = awl[(kk*2+0)*64 + l];
        u32x4 a1 = awl[(kk*2+1)*64 + l];
        acc0 = __builtin_amdgcn_mfma_f32_16x16x32_f16(
                   __builtin_bit_cast(f16x8, a0), __builtin_bit_cast(f16x8, bv), acc0, 0, 0, 0);
        acc1 = __builtin_amdgcn_mfma_f32_16x16x32_f16(
                   __builtin_bit_cast(f16x8, a1), __builtin_bit_cast(f16x8, bv), acc1, 0, 0, 0);
    }

    int gpix = (b*HH + ho)*WW + wo;
#pragma unroll
    for (int r = 0; r < 4; ++r) {
        int oc0 = hi*4 + r;                       // 0..15: dy/dx planes
        float v0 = acc0[r] + ob[oc0];
        int plane0 = (oc0 & 1)*9 + (oc0 >> 1);
        tap[plane0*NPIX + gpix] = v0;
        int oc1 = 16 + hi*4 + r;                  // 16..31
        if (oc1 < 27) {
            float v1 = acc1[r] + ob[oc1];
            float vv; int plane1;
            if (oc1 < 18) { plane1 = (oc1 & 1)*9 + (oc1 >> 1); vv = v1; }
            else { plane1 = oc1; vv = 1.f / (1.f + __expf(-v1)); }
            tap[plane1*NPIX + gpix] = vv;
        }
    }
}

// ---------------------------------------------------------------------------
// packed-f16 bilinear lerp: r = a*w0 + b*w1 + c*w2 + d*w3 (v_pk_fma_f16)
__device__ inline f16x8 lerp8h(u32x4 a, u32x4 b, u32x4 c, u32x4 d,
                               f16x8 w0, f16x8 w1, f16x8 w2, f16x8 w3) {
    f16x8 av = __builtin_bit_cast(f16x8, a);
    f16x8 bv = __builtin_bit_cast(f16x8, b);
    f16x8 cv = __builtin_bit_cast(f16x8, c);
    f16x8 dv = __builtin_bit_cast(f16x8, d);
    return av*w0 + bv*w1 + cv*w2 + dv*w3;
}

__device__ inline f16x8 splat8(float s) {
    _Float16 h = (_Float16)s;
    return (f16x8){h, h, h, h, h, h, h, h};
}

// ---------------------------------------------------------------------------
// K2: fused deformable sampling + f16 MFMA GEMM, BARRIER-FREE main loop.
// 256 blocks x 1024 threads (16 waves = one 256-px row). ALL 9 taps' A-frags
// staged once into 144KB LDS (one barrier), then waves run fully independent:
// per wave/tap {8 gathers -> lerp -> 16 ds_read + 16 MFMA}, 1-tap-ahead pipeline.
__global__ __launch_bounds__(1024, 4) void k_main(const unsigned int* __restrict__ xtb,
                                                  const float* __restrict__ tap,
                                                  const unsigned short* __restrict__ wtF,
                                                  float* __restrict__ out) {
    __shared__ u32x4 wlds[9216];   // 144 KB: all 9 taps, 16KB each
    int bx = xcd_swz256(blockIdx.x);
    int ho = bx & 63, b = bx >> 6;
    int tid = threadIdx.x;
    int w = tid >> 6;              // 0..15 -> pixel group
    int l = tid & 63;
    int pxl = l & 15, hi = l >> 4;
    int wo = w*16 + pxl;
    int gpix = (b*HH + ho)*WW + wo;

    // stage ALL taps' A-fragments (linear copy; swizzle pre-baked in global)
    const u32x4* wsrc = (const u32x4*)wtF;
#pragma unroll
    for (int i = 0; i < 9; ++i) wlds[tid + i*1024] = wsrc[tid + i*1024];

    // A-fragment swizzled LDS byte offsets (within a tap's 16KB)
    int lo0 = (hi*16)      ^ ((l & 7) << 4);
    int lo1 = (64 + hi*16) ^ ((l & 7) << 4);
    int abase = pxl * 128;

    // hoist all tap params (27 independent loads, one latency)
    float tdy[9], tdx[9], tm[9];
#pragma unroll
    for (int k = 0; k < 9; ++k) {
        tdy[k] = tap[k*NPIX + gpix];
        tdx[k] = tap[(9+k)*NPIX + gpix];
        tm[k]  = tap[(18+k)*NPIX + gpix];
    }

    // compute addresses + issue the 8 gathers + lerp weights for tap k
    auto issue_tap = [&](int k, u32x4* G, float* W) {
        float dy = tdy[k], dx = tdx[k], m = tm[k];
        int ki = k / 3, kj = k - ki*3;
        float py  = dy + (float)(ho - 1 + ki);
        float pxf = dx + (float)(wo - 1 + kj);
        float y0f = floorf(py), x0f = floorf(pxf);
        float ly = py - y0f, lxf = pxf - x0f;
        int y0 = (int)y0f, x0 = (int)x0f;
        int y1 = y0 + 1,  x1 = x0 + 1;
        bool vy0 = (y0 >= 0) && (y0 < HH), vy1 = (y1 >= 0) && (y1 < HH);
        bool vx0 = (x0 >= 0) && (x0 < WW), vx1 = (x1 >= 0) && (x1 < WW);
        float hy = 1.f - ly, hx = 1.f - lxf;
        W[0] = (vy0 && vx0) ? hy*hx*m : 0.f;
        W[1] = (vy0 && vx1) ? hy*lxf*m : 0.f;
        W[2] = (vy1 && vx0) ? ly*hx*m : 0.f;
        W[3] = (vy1 && vx1) ? ly*lxf*m : 0.f;
        int yc0 = min(max(y0, 0), HH-1), yc1 = min(max(y1, 0), HH-1);
        int xc0 = min(max(x0, 0), WW-1), xc1 = min(max(x1, 0), WW-1);
        const u32x4* p00 = (const u32x4*)(xtb + ((b*HH + yc0)*WW + xc0)*32);
        const u32x4* p01 = (const u32x4*)(xtb + ((b*HH + yc0)*WW + xc1)*32);
        const u32x4* p10 = (const u32x4*)(xtb + ((b*HH + yc1)*WW + xc0)*32);
        const u32x4* p11 = (const u32x4*)(xtb + ((b*HH + yc1)*WW + xc1)*32);
        G[0] = p00[hi];   G[1] = p01[hi];   G[2] = p10[hi];   G[3] = p11[hi];
        G[4] = p00[hi+4]; G[5] = p01[hi+4]; G[6] = p10[hi+4]; G[7] = p11[hi+4];
    };

    __syncthreads();   // staging visible; the ONLY barrier

    f32x4 acc[8];
#pragma unroll
    for (int i = 0; i < 8; ++i) acc[i] = (f32x4){0.f, 0.f, 0.f, 0.f};

    u32x4 GA[8], GB[8];
    float WA[4], WB[4];
    issue_tap(0, GA, WA);

#pragma unroll
    for (int k = 0; k < 9; ++k) {
        u32x4 *G, *Gn; float *W, *Wn;
        if (k & 1) { G = GB; W = WB; Gn = GA; Wn = WA; }
        else       { G = GA; W = WA; Gn = GB; Wn = WB; }

        // issue next tap's gathers (latency hides under this tap's lerp+MFMA)
        if (k < 8) issue_tap(k+1, Gn, Wn);

        // ---- lerp tap k -> B fragments (packed f16 math)
        f16x8 w0v = splat8(W[0]), w1v = splat8(W[1]), w2v = splat8(W[2]), w3v = splat8(W[3]);
        f16x8 bf0 = lerp8h(G[0], G[1], G[2], G[3], w0v, w1v, w2v, w3v);
        f16x8 bf1 = lerp8h(G[4], G[5], G[6], G[7], w0v, w1v, w2v, w3v);

        // ---- 16 MFMA from this tap's LDS buffer (no barriers, waves free-run)
        const char* wb = (const char*)wlds + k*16384;
#pragma unroll
        for (int mi = 0; mi < 8; ++mi) {
            u32x4 a0 = *(const u32x4*)(wb + (abase + lo0 + mi*2048));
            u32x4 a1 = *(const u32x4*)(wb + (abase + lo1 + mi*2048));
            acc[mi] = __builtin_amdgcn_mfma_f32_16x16x32_f16(
                          __builtin_bit_cast(f16x8, a0), bf0, acc[mi], 0, 0, 0);
            acc[mi] = __builtin_amdgcn_mfma_f32_16x16x32_f16(
                          __builtin_bit_cast(f16x8, a1), bf1, acc[mi], 0, 0, 0);
        }
    }

#pragma unroll
    for (int mi = 0; mi < 8; ++mi) {
#pragma unroll
        for (int r = 0; r < 4; ++r) {
            int o = mi*16 + hi*4 + r;     // C/D: col=lane&15(px), row=(lane>>4)*4+reg
            out[((b*CO + o)*HH + ho)*WW + wo] = acc[mi][r];
        }
    }
}

// ---------------------------------------------------------------------------
extern "C" void kernel_launch(void* const* d_in, const int* in_sizes, int n_in,
                              void* d_out, int out_size, void* d_ws, size_t ws_size,
                              hipStream_t stream) {
    const float* x  = (const float*)d_in[0];
    const float* ow = (const float*)d_in[1];
    const float* ob = (const float*)d_in[2];
    const float* wm = (const float*)d_in[3];
    float* outp = (float*)d_out;

    float* ws   = (float*)d_ws;
    unsigned int* xtb = (unsigned int*)(ws + XTB_OFF);
    float* tap  = ws + TAP_OFF;
    unsigned short* owb = (unsigned short*)(ws + OWB_OFF);
    unsigned short* wtF = (unsigned short*)(ws + WTF_OFF);

    k_transpose_x<<<1024, 256, 0, stream>>>(x, xtb);
    k_prep_w<<<360, 256, 0, stream>>>(ow, wm, owb, wtF);
    k_offconv<<<1024, 256, 0, stream>>>(xtb, owb, ob, tap);
    k_main<<<256, 1024, 0, stream>>>(xtb, tap, wtF, outp);
}

// Round 14
// 64.748 us; speedup vs baseline: 1.2015x; 1.0043x over previous
//
#include <hip/hip_runtime.h>
#include <math.h>

// Problem constants
#define BB   4
#define CIN  64
#define HH   64
#define WW   256
#define CO   128
#define NPIX (BB*HH*WW)       // 65536

typedef float  f32x4 __attribute__((ext_vector_type(4)));
typedef unsigned int u32x4 __attribute__((ext_vector_type(4)));
typedef _Float16 f16x8 __attribute__((ext_vector_type(8)));
typedef _Float16 f16x2 __attribute__((ext_vector_type(2)));

// Workspace layout (float/u32 slots). Total ~15.7 MB.
#define XTB_OFF  0
#define XTB_SZ   (NPIX*32)            // 2097152 u32: f16 x as [b][y][x][c], 2ch/u32
#define TAP_OFF  (XTB_OFF + XTB_SZ)
#define TAP_SZ   (27*NPIX)            // planes: dy[9], dx[9], mask[9] (f32)
#define OWB_OFF  (TAP_OFF + TAP_SZ)
#define OWB_SZ   9216                 // 18432 f16: offconv A-fragments [18][2][64][8]
#define WTF_OFF  (OWB_OFF + OWB_SZ)   // ushort[9][8192] f16 A-frag, XOR-swizzled

// XCD-aware block swizzles (8 XCDs).
__device__ inline int xcd_swz(int bid)    { return (bid & 7) * 128 + (bid >> 3); }
__device__ inline int xcd_swz256(int bid) { return (bid & 7) * 32  + (bid >> 3); }

// ---------------------------------------------------------------------------
// K0x: x [B][C][H][W] f32 -> xtb [B][H][W][C] f16 (packed 2ch/u32, linear order)
__global__ __launch_bounds__(256) void k_transpose_x(const float* __restrict__ x,
                                                     unsigned int* __restrict__ xtb) {
    __shared__ float t[64][65];
    int bx = xcd_swz(blockIdx.x);  // 1024 blocks: (b, y, xtile)
    int x0 = (bx & 3) * 64;
    int y  = (bx >> 2) & 63;
    int b  = bx >> 8;
    int tid = threadIdx.x;
    int lx = tid & 63, gy = tid >> 6;
#pragma unroll
    for (int i = 0; i < 16; ++i) {
        int c = i * 4 + gy;
        t[c][lx] = x[((b*CIN + c)*HH + y)*WW + x0 + lx];
    }
    __syncthreads();
    int px = tid & 63, cg = tid >> 6;      // 16 channels per cg
    u32x4 r0, r1;
#pragma unroll
    for (int j = 0; j < 4; ++j) {
        f16x2 p, q;
        p[0] = (_Float16)t[cg*16 + 2*j][px];
        p[1] = (_Float16)t[cg*16 + 2*j + 1][px];
        q[0] = (_Float16)t[cg*16 + 8 + 2*j][px];
        q[1] = (_Float16)t[cg*16 + 8 + 2*j + 1][px];
        r0[j] = __builtin_bit_cast(unsigned int, p);
        r1[j] = __builtin_bit_cast(unsigned int, q);
    }
    u32x4* dst = (u32x4*)(xtb + (((b*HH + y)*WW) + x0 + px)*32 + cg*8);
    dst[0] = r0; dst[1] = r1;
}

// ---------------------------------------------------------------------------
// K0w: weight prep (f16).
__global__ __launch_bounds__(256) void k_prep_w(const float* __restrict__ ow,
                                                const float* __restrict__ wm,
                                                unsigned short* __restrict__ owb,
                                                unsigned short* __restrict__ wtF) {
    const int n1 = 18432;
    const int n2 = 9*CO*CIN;
    for (int i = blockIdx.x*blockDim.x + threadIdx.x;
         i < n1 + n2; i += gridDim.x*blockDim.x) {
        if (i < n1) {
            int j = i & 7, l = (i >> 3) & 63, mi = (i >> 9) & 1, kk = i >> 10;
            int oc = mi*16 + (l & 15);
            int k  = kk*32 + (l >> 4)*8 + j;
            int t = k >> 6, c = k & 63;
            float v = (oc < 27) ? ow[(oc*CIN + c)*9 + t] : 0.f;
            owb[i] = __builtin_bit_cast(unsigned short, (_Float16)v);
        } else {
            int j = i - n1;
            int k = j / (CO*CIN);
            int r = j % (CO*CIN);      // r = o*64 + c
            int o = r / CIN, c = r % CIN;
            float v = wm[(o*CIN + c)*9 + k];
            wtF[k*8192 + (r ^ ((o & 7) << 3))] =
                __builtin_bit_cast(unsigned short, (_Float16)v);
        }
    }
}

// ---------------------------------------------------------------------------
// K1: offset conv via f16 MFMA. 1024 blocks x 4 waves; wave = 32(oc) x 16(px).
__global__ __launch_bounds__(256) void k_offconv(const unsigned int* __restrict__ xtb,
                                                 const unsigned short* __restrict__ owb,
                                                 const float* __restrict__ ob,
                                                 float* __restrict__ tap) {
    __shared__ u32x4 awl[2304];        // 36864 B
    int bx = xcd_swz(blockIdx.x);      // 1024: (b, ho, wtile)
    int wtile = bx & 3, ho = (bx >> 2) & 63, b = bx >> 8;
    int tid = threadIdx.x;
    {
        const u32x4* asrc = (const u32x4*)owb;
#pragma unroll
        for (int i = 0; i < 9; ++i) awl[tid + i*256] = asrc[tid + i*256];
    }
    __syncthreads();
    int w = tid >> 6, l = tid & 63;
    int pxl = l & 15, hi = l >> 4;
    int wo = wtile*64 + w*16 + pxl;

    f32x4 acc0 = (f32x4){0.f,0.f,0.f,0.f}, acc1 = (f32x4){0.f,0.f,0.f,0.f};
#pragma unroll
    for (int kk = 0; kk < 18; ++kk) {
        const int t = kk >> 1;
        const int ki = t / 3, kj = t % 3;
        int y  = ho + ki - 1;
        int xx = wo + kj - 1;
        bool v = (y >= 0) && (y < HH) && (xx >= 0) && (xx < WW);
        int yc = min(max(y, 0), HH-1), xc = min(max(xx, 0), WW-1);
        const u32x4* p = (const u32x4*)(xtb + ((b*HH + yc)*WW + xc)*32);
        u32x4 bv = p[(kk & 1)*4 + hi];
        if (!v) bv = (u32x4){0u,0u,0u,0u};
        u32x4 a0 = awl[(kk*2+0)*64 + l];
        u32x4 a1 = awl[(kk*2+1)*64 + l];
        acc0 = __builtin_amdgcn_mfma_f32_16x16x32_f16(
                   __builtin_bit_cast(f16x8, a0), __builtin_bit_cast(f16x8, bv), acc0, 0, 0, 0);
        acc1 = __builtin_amdgcn_mfma_f32_16x16x32_f16(
                   __builtin_bit_cast(f16x8, a1), __builtin_bit_cast(f16x8, bv), acc1, 0, 0, 0);
    }

    int gpix = (b*HH + ho)*WW + wo;
#pragma unroll
    for (int r = 0; r < 4; ++r) {
        int oc0 = hi*4 + r;                       // 0..15: dy/dx planes
        float v0 = acc0[r] + ob[oc0];
        int plane0 = (oc0 & 1)*9 + (oc0 >> 1);
        tap[plane0*NPIX + gpix] = v0;
        int oc1 = 16 + hi*4 + r;                  // 16..31
        if (oc1 < 27) {
            float v1 = acc1[r] + ob[oc1];
            float vv; int plane1;
            if (oc1 < 18) { plane1 = (oc1 & 1)*9 + (oc1 >> 1); vv = v1; }
            else { plane1 = oc1; vv = 1.f / (1.f + __expf(-v1)); }
            tap[plane1*NPIX + gpix] = vv;
        }
    }
}

// ---------------------------------------------------------------------------
__device__ inline f16x8 lerp8h(u32x4 a, u32x4 b, u32x4 c, u32x4 d,
                               f16x8 w0, f16x8 w1, f16x8 w2, f16x8 w3) {
    f16x8 av = __builtin_bit_cast(f16x8, a);
    f16x8 bv = __builtin_bit_cast(f16x8, b);
    f16x8 cv = __builtin_bit_cast(f16x8, c);
    f16x8 dv = __builtin_bit_cast(f16x8, d);
    return av*w0 + bv*w1 + cv*w2 + dv*w3;
}

__device__ inline f16x8 splat8(float s) {
    _Float16 h = (_Float16)s;
    return (f16x8){h, h, h, h, h, h, h, h};
}

// ---------------------------------------------------------------------------
// K2: fused deformable sampling + f16 MFMA GEMM, DEEP-PIPELINED (half-tap).
// 256 blocks x 1024 threads (16 waves, one 256-px row). All 9 taps' A-frags in
// 144KB LDS (one barrier). Main loop: 18 halves; half h = tap h>>1, part h&1
// (4 gathers + lerp + 8 MFMA). Gathers issued with 3-half (~1.5 tap) lead via
// G[4] rotation; per-tap addresses/weights computed 1.5 taps ahead (idx/wts[3]);
// tap params ping-pong prefetched one tap ahead of that (par0: even taps,
// par1: odd taps — consumer of kt always reads the reg loaded with kt).
__global__ __launch_bounds__(1024, 4) void k_main(const unsigned int* __restrict__ xtb,
                                                  const float* __restrict__ tap,
                                                  const unsigned short* __restrict__ wtF,
                                                  float* __restrict__ out) {
    __shared__ u32x4 wlds[9216];   // 144 KB: all 9 taps, 16KB each
    int bx = xcd_swz256(blockIdx.x);
    int ho = bx & 63, b = bx >> 6;
    int tid = threadIdx.x;
    int w = tid >> 6;              // 0..15 -> pixel group
    int l = tid & 63;
    int pxl = l & 15, hi = l >> 4;
    int wo = w*16 + pxl;
    int gpix = (b*HH + ho)*WW + wo;

    // stage ALL taps' A-fragments (linear copy; swizzle pre-baked in global)
    const u32x4* wsrc = (const u32x4*)wtF;
#pragma unroll
    for (int i = 0; i < 9; ++i) wlds[tid + i*1024] = wsrc[tid + i*1024];

    // A-fragment swizzled LDS byte offsets (within a tap's 16KB)
    int lo0 = (hi*16)      ^ ((l & 7) << 4);
    int lo1 = (64 + hi*16) ^ ((l & 7) << 4);
    int abase = pxl * 128;

    const u32x4* xtb4 = (const u32x4*)xtb;

    // rotating pipeline state (all statically indexed after unroll)
    int   idx[3][4];     // corner row base (u32x4 units), per tap%3
    float wts[3][4];     // bilinear*mask weights, per tap%3
    u32x4 G[4][4];       // gathered corners, per half%4
    float pdy0, pdx0, pm0, pdy1, pdx1, pm1;   // ping-pong tap-param prefetch

    auto load_par0 = [&](int k) { pdy0 = tap[k*NPIX+gpix]; pdx0 = tap[(9+k)*NPIX+gpix]; pm0 = tap[(18+k)*NPIX+gpix]; };
    auto load_par1 = [&](int k) { pdy1 = tap[k*NPIX+gpix]; pdx1 = tap[(9+k)*NPIX+gpix]; pm1 = tap[(18+k)*NPIX+gpix]; };

    auto tap_addr = [&](int k, float dy, float dx, float m) {
        int ki = k / 3, kj = k - ki*3;
        float py  = dy + (float)(ho - 1 + ki);
        float pxf = dx + (float)(wo - 1 + kj);
        float y0f = floorf(py), x0f = floorf(pxf);
        float ly = py - y0f, lxf = pxf - x0f;
        int y0 = (int)y0f, x0 = (int)x0f;
        int y1 = y0 + 1,  x1 = x0 + 1;
        bool vy0 = (y0 >= 0) && (y0 < HH), vy1 = (y1 >= 0) && (y1 < HH);
        bool vx0 = (x0 >= 0) && (x0 < WW), vx1 = (x1 >= 0) && (x1 < WW);
        float hy = 1.f - ly, hx = 1.f - lxf;
        int s = k % 3;
        wts[s][0] = (vy0 && vx0) ? hy*hx*m : 0.f;
        wts[s][1] = (vy0 && vx1) ? hy*lxf*m : 0.f;
        wts[s][2] = (vy1 && vx0) ? ly*hx*m : 0.f;
        wts[s][3] = (vy1 && vx1) ? ly*lxf*m : 0.f;
        int yc0 = min(max(y0, 0), HH-1), yc1 = min(max(y1, 0), HH-1);
        int xc0 = min(max(x0, 0), WW-1), xc1 = min(max(x1, 0), WW-1);
        idx[s][0] = ((b*HH + yc0)*WW + xc0)*8;
        idx[s][1] = ((b*HH + yc0)*WW + xc1)*8;
        idx[s][2] = ((b*HH + yc1)*WW + xc0)*8;
        idx[s][3] = ((b*HH + yc1)*WW + xc1)*8;
    };

    auto issue_half = [&](int h) {
        int k = h >> 1, p = h & 1;
        const int* id = idx[k % 3];
        u32x4* g = G[h & 3];
        int ch = p*4 + hi;
        g[0] = xtb4[id[0] + ch];
        g[1] = xtb4[id[1] + ch];
        g[2] = xtb4[id[2] + ch];
        g[3] = xtb4[id[3] + ch];
    };

    // ---- prologue: taps 0,1 addressed; halves 0,1,2 in flight; tap2 params loading
    load_par0(0);
    load_par1(1);
    tap_addr(0, pdy0, pdx0, pm0);
    issue_half(0);
    issue_half(1);
    tap_addr(1, pdy1, pdx1, pm1);
    load_par0(2);
    issue_half(2);

    __syncthreads();   // staging visible; the ONLY barrier (gathers stay in flight)

    f32x4 acc[8];
#pragma unroll
    for (int i = 0; i < 8; ++i) acc[i] = (f32x4){0.f, 0.f, 0.f, 0.f};

#pragma unroll
    for (int h = 0; h < 18; ++h) {
        const int k = h >> 1, p = h & 1;
        // issue side: at odd h, compute tap (h+3)/2's addresses + ping-pong refill
        if (h + 3 < 18) {
            if (((h + 3) & 1) == 0) {
                int kt = (h + 3) >> 1;            // k+2
                if (kt & 1) { tap_addr(kt, pdy1, pdx1, pm1); if (kt+1 < 9) load_par0(kt+1); }
                else        { tap_addr(kt, pdy0, pdx0, pm0); if (kt+1 < 9) load_par1(kt+1); }
            }
            issue_half(h + 3);
        }

        // consume half h: lerp -> one B fragment -> 8 MFMA
        const float* W = wts[k % 3];
        f16x8 bf = lerp8h(G[h & 3][0], G[h & 3][1], G[h & 3][2], G[h & 3][3],
                          splat8(W[0]), splat8(W[1]), splat8(W[2]), splat8(W[3]));
        const char* wb = (const char*)wlds + k*16384;
        const int lo = p ? lo1 : lo0;
#pragma unroll
        for (int mi = 0; mi < 8; ++mi) {
            u32x4 a = *(const u32x4*)(wb + (abase + lo + mi*2048));
            acc[mi] = __builtin_amdgcn_mfma_f32_16x16x32_f16(
                          __builtin_bit_cast(f16x8, a), bf, acc[mi], 0, 0, 0);
        }
    }

#pragma unroll
    for (int mi = 0; mi < 8; ++mi) {
#pragma unroll
        for (int r = 0; r < 4; ++r) {
            int o = mi*16 + hi*4 + r;     // C/D: col=lane&15(px), row=(lane>>4)*4+reg
            out[((b*CO + o)*HH + ho)*WW + wo] = acc[mi][r];
        }
    }
}

// ---------------------------------------------------------------------------
extern "C" void kernel_launch(void* const* d_in, const int* in_sizes, int n_in,
                              void* d_out, int out_size, void* d_ws, size_t ws_size,
                              hipStream_t stream) {
    const float* x  = (const float*)d_in[0];
    const float* ow = (const float*)d_in[1];
    const float* ob = (const float*)d_in[2];
    const float* wm = (const float*)d_in[3];
    float* outp = (float*)d_out;

    float* ws   = (float*)d_ws;
    unsigned int* xtb = (unsigned int*)(ws + XTB_OFF);
    float* tap  = ws + TAP_OFF;
    unsigned short* owb = (unsigned short*)(ws + OWB_OFF);
    unsigned short* wtF = (unsigned short*)(ws + WTF_OFF);

    k_transpose_x<<<1024, 256, 0, stream>>>(x, xtb);
    k_prep_w<<<360, 256, 0, stream>>>(ow, wm, owb, wtF);
    k_offconv<<<1024, 256, 0, stream>>>(xtb, owb, ob, tap);
    k_main<<<256, 1024, 0, stream>>>(xtb, tap, wtF, outp);
}

// Round 15
// 62.902 us; speedup vs baseline: 1.2368x; 1.0293x over previous
//
#include <hip/hip_runtime.h>
#include <math.h>

// Problem constants
#define BB   4
#define CIN  64
#define HH   64
#define WW   256
#define CO   128
#define NPIX (BB*HH*WW)       // 65536

typedef float  f32x4 __attribute__((ext_vector_type(4)));
typedef unsigned int u32x4 __attribute__((ext_vector_type(4)));
typedef _Float16 f16x8 __attribute__((ext_vector_type(8)));
typedef _Float16 f16x2 __attribute__((ext_vector_type(2)));

// Workspace layout (float/u32 slots). Total ~8.5 MB.
#define XTB_OFF  0
#define XTB_SZ   (NPIX*32)            // 2097152 u32: f16 x as [b][y][x][c], 2ch/u32
#define OWB_OFF  (XTB_OFF + XTB_SZ)
#define OWB_SZ   9216                 // 18432 f16: offconv A-fragments [18][2][64][8]
#define WTF_OFF  (OWB_OFF + OWB_SZ)   // ushort[9][8192] f16 A-frag, XOR-swizzled

// XCD-aware block swizzles (8 XCDs).
__device__ inline int xcd_swz(int bid)    { return (bid & 7) * 128 + (bid >> 3); }
__device__ inline int xcd_swz256(int bid) { return (bid & 7) * 32  + (bid >> 3); }

// ---------------------------------------------------------------------------
// K0x: x [B][C][H][W] f32 -> xtb [B][H][W][C] f16 (packed 2ch/u32, linear order)
__global__ __launch_bounds__(256) void k_transpose_x(const float* __restrict__ x,
                                                     unsigned int* __restrict__ xtb) {
    __shared__ float t[64][65];
    int bx = xcd_swz(blockIdx.x);  // 1024 blocks: (b, y, xtile)
    int x0 = (bx & 3) * 64;
    int y  = (bx >> 2) & 63;
    int b  = bx >> 8;
    int tid = threadIdx.x;
    int lx = tid & 63, gy = tid >> 6;
#pragma unroll
    for (int i = 0; i < 16; ++i) {
        int c = i * 4 + gy;
        t[c][lx] = x[((b*CIN + c)*HH + y)*WW + x0 + lx];
    }
    __syncthreads();
    int px = tid & 63, cg = tid >> 6;      // 16 channels per cg
    u32x4 r0, r1;
#pragma unroll
    for (int j = 0; j < 4; ++j) {
        f16x2 p, q;
        p[0] = (_Float16)t[cg*16 + 2*j][px];
        p[1] = (_Float16)t[cg*16 + 2*j + 1][px];
        q[0] = (_Float16)t[cg*16 + 8 + 2*j][px];
        q[1] = (_Float16)t[cg*16 + 8 + 2*j + 1][px];
        r0[j] = __builtin_bit_cast(unsigned int, p);
        r1[j] = __builtin_bit_cast(unsigned int, q);
    }
    u32x4* dst = (u32x4*)(xtb + (((b*HH + y)*WW) + x0 + px)*32 + cg*8);
    dst[0] = r0; dst[1] = r1;
}

// ---------------------------------------------------------------------------
// K0w: weight prep (f16).
//  owb: offconv A-fragments. elem ((kk*2+mi)*64+l)*8+j = W[oc=mi*16+(l&15)]
//       [k=kk*32+(l>>4)*8+j], k=t*64+c, 0 for oc>=27.
//  wtF [k][ (o*64+c) ^ ((o&7)<<3) ]: f16, A-fragment rows pre-swizzled
__global__ __launch_bounds__(256) void k_prep_w(const float* __restrict__ ow,
                                                const float* __restrict__ wm,
                                                unsigned short* __restrict__ owb,
                                                unsigned short* __restrict__ wtF) {
    const int n1 = 18432;
    const int n2 = 9*CO*CIN;
    for (int i = blockIdx.x*blockDim.x + threadIdx.x;
         i < n1 + n2; i += gridDim.x*blockDim.x) {
        if (i < n1) {
            int j = i & 7, l = (i >> 3) & 63, mi = (i >> 9) & 1, kk = i >> 10;
            int oc = mi*16 + (l & 15);
            int k  = kk*32 + (l >> 4)*8 + j;
            int t = k >> 6, c = k & 63;
            float v = (oc < 27) ? ow[(oc*CIN + c)*9 + t] : 0.f;
            owb[i] = __builtin_bit_cast(unsigned short, (_Float16)v);
        } else {
            int j = i - n1;
            int k = j / (CO*CIN);
            int r = j % (CO*CIN);      // r = o*64 + c
            int o = r / CIN, c = r % CIN;
            float v = wm[(o*CIN + c)*9 + k];
            wtF[k*8192 + (r ^ ((o & 7) << 3))] =
                __builtin_bit_cast(unsigned short, (_Float16)v);
        }
    }
}

// ---------------------------------------------------------------------------
__device__ inline f16x8 lerp8h(u32x4 a, u32x4 b, u32x4 c, u32x4 d,
                               f16x8 w0, f16x8 w1, f16x8 w2, f16x8 w3) {
    f16x8 av = __builtin_bit_cast(f16x8, a);
    f16x8 bv = __builtin_bit_cast(f16x8, b);
    f16x8 cv = __builtin_bit_cast(f16x8, c);
    f16x8 dv = __builtin_bit_cast(f16x8, d);
    return av*w0 + bv*w1 + cv*w2 + dv*w3;
}

__device__ inline f16x8 splat8(float s) {
    _Float16 h = (_Float16)s;
    return (f16x8){h, h, h, h, h, h, h, h};
}

// ---------------------------------------------------------------------------
// K2: FUSED offset-conv + deformable sampling + f16 MFMA GEMM.
// 256 blocks x 1024 threads (16 waves, one 256-px row each; wave = 16 px).
// Phase A (per wave): 27-ch offset conv via 36 MFMAs; A-frags (owb) streamed
//   from global (lane-linear, L1-hot); epilogue -> bias/sigmoid/permute ->
//   f16 tap params into 14KB LDS scratch (wave-local; LDS in-order => no bar).
// Phase B: r14's deep-pipelined main loop; tap params read from LDS scratch.
// Weights (144KB, all 9 taps) staged after phase A; ONE lgkm-only barrier.
__global__ __launch_bounds__(1024, 4) void k_fused(const unsigned int* __restrict__ xtb,
                                                   const unsigned short* __restrict__ owb,
                                                   const float* __restrict__ ob,
                                                   const unsigned short* __restrict__ wtF,
                                                   float* __restrict__ out) {
    __shared__ u32x4 wlds[9216];        // 144 KB: all 9 taps' main A-frags
    __shared__ _Float16 pscr[7168];     // 14 KB: [256 px][28] tap params (27 used)
    int bx = xcd_swz256(blockIdx.x);
    int ho = bx & 63, b = bx >> 6;
    int tid = threadIdx.x;
    int w = tid >> 6;              // 0..15 -> pixel group
    int l = tid & 63;
    int pxl = l & 15, hi = l >> 4;
    int wo = w*16 + pxl;

    const u32x4* xtb4 = (const u32x4*)xtb;
    int pbase = (w*16 + pxl) * 28;

    // ======== Phase A: offset conv for this wave's 16 px ========
    {
        const u32x4* asrc = (const u32x4*)owb;
        f32x4 acc0 = (f32x4){0.f,0.f,0.f,0.f}, acc1 = (f32x4){0.f,0.f,0.f,0.f};
#pragma unroll
        for (int kk = 0; kk < 18; ++kk) {
            const int t = kk >> 1;
            const int ki = t / 3, kj = t % 3;
            int y  = ho + ki - 1;
            int xx = wo + kj - 1;
            bool v = (y >= 0) && (y < HH) && (xx >= 0) && (xx < WW);
            int yc = min(max(y, 0), HH-1), xc = min(max(xx, 0), WW-1);
            u32x4 bv = xtb4[((b*HH + yc)*WW + xc)*8 + (kk & 1)*4 + hi];
            if (!v) bv = (u32x4){0u,0u,0u,0u};
            u32x4 a0 = asrc[(kk*2+0)*64 + l];
            u32x4 a1 = asrc[(kk*2+1)*64 + l];
            acc0 = __builtin_amdgcn_mfma_f32_16x16x32_f16(
                       __builtin_bit_cast(f16x8, a0), __builtin_bit_cast(f16x8, bv), acc0, 0, 0, 0);
            acc1 = __builtin_amdgcn_mfma_f32_16x16x32_f16(
                       __builtin_bit_cast(f16x8, a1), __builtin_bit_cast(f16x8, bv), acc1, 0, 0, 0);
        }
        // epilogue: bias + plane-permute + sigmoid -> f16 scratch (wave-local)
#pragma unroll
        for (int r = 0; r < 4; ++r) {
            int oc0 = hi*4 + r;                       // 0..15: dy/dx planes
            float v0 = acc0[r] + ob[oc0];
            pscr[pbase + (oc0 & 1)*9 + (oc0 >> 1)] = (_Float16)v0;
            int oc1 = 16 + hi*4 + r;                  // 16..31
            if (oc1 < 27) {
                float v1 = acc1[r] + ob[oc1];
                if (oc1 < 18) pscr[pbase + (oc1 & 1)*9 + (oc1 >> 1)] = (_Float16)v1;
                else          pscr[pbase + oc1] = (_Float16)(1.f / (1.f + __expf(-v1)));
            }
        }
    }
    // LDS ops within a wave complete in order -> this wave's reads below see
    // its own writes; params are wave-local (all 4 hi-lanes of px are here).

    // ======== stage main-conv weights (all 9 taps) ========
    const u32x4* wsrc = (const u32x4*)wtF;
#pragma unroll
    for (int i = 0; i < 9; ++i) wlds[tid + i*1024] = wsrc[tid + i*1024];

    // A-fragment swizzled LDS byte offsets (within a tap's 16KB)
    int lo0 = (hi*16)      ^ ((l & 7) << 4);
    int lo1 = (64 + hi*16) ^ ((l & 7) << 4);
    int abase = pxl * 128;

    // ======== Phase B: pipelined sampling + GEMM (r14 structure) ========
    int   idx[3][4];     // corner row base (u32x4 units), per tap%3
    float wts[3][4];     // bilinear*mask weights, per tap%3
    u32x4 G[4][4];       // gathered corners, per half%4
    float pdy0, pdx0, pm0, pdy1, pdx1, pm1;   // ping-pong tap-param prefetch

    auto load_par0 = [&](int k) { pdy0 = (float)pscr[pbase+k]; pdx0 = (float)pscr[pbase+9+k]; pm0 = (float)pscr[pbase+18+k]; };
    auto load_par1 = [&](int k) { pdy1 = (float)pscr[pbase+k]; pdx1 = (float)pscr[pbase+9+k]; pm1 = (float)pscr[pbase+18+k]; };

    auto tap_addr = [&](int k, float dy, float dx, float m) {
        int ki = k / 3, kj = k - ki*3;
        float py  = dy + (float)(ho - 1 + ki);
        float pxf = dx + (float)(wo - 1 + kj);
        float y0f = floorf(py), x0f = floorf(pxf);
        float ly = py - y0f, lxf = pxf - x0f;
        int y0 = (int)y0f, x0 = (int)x0f;
        int y1 = y0 + 1,  x1 = x0 + 1;
        bool vy0 = (y0 >= 0) && (y0 < HH), vy1 = (y1 >= 0) && (y1 < HH);
        bool vx0 = (x0 >= 0) && (x0 < WW), vx1 = (x1 >= 0) && (x1 < WW);
        float hy = 1.f - ly, hx = 1.f - lxf;
        int s = k % 3;
        wts[s][0] = (vy0 && vx0) ? hy*hx*m : 0.f;
        wts[s][1] = (vy0 && vx1) ? hy*lxf*m : 0.f;
        wts[s][2] = (vy1 && vx0) ? ly*hx*m : 0.f;
        wts[s][3] = (vy1 && vx1) ? ly*lxf*m : 0.f;
        int yc0 = min(max(y0, 0), HH-1), yc1 = min(max(y1, 0), HH-1);
        int xc0 = min(max(x0, 0), WW-1), xc1 = min(max(x1, 0), WW-1);
        idx[s][0] = ((b*HH + yc0)*WW + xc0)*8;
        idx[s][1] = ((b*HH + yc0)*WW + xc1)*8;
        idx[s][2] = ((b*HH + yc1)*WW + xc0)*8;
        idx[s][3] = ((b*HH + yc1)*WW + xc1)*8;
    };

    auto issue_half = [&](int h) {
        int k = h >> 1, p = h & 1;
        const int* id = idx[k % 3];
        u32x4* g = G[h & 3];
        int ch = p*4 + hi;
        g[0] = xtb4[id[0] + ch];
        g[1] = xtb4[id[1] + ch];
        g[2] = xtb4[id[2] + ch];
        g[3] = xtb4[id[3] + ch];
    };

    // prologue: taps 0,1 addressed; halves 0,1,2 in flight; tap2 params loading
    load_par0(0);
    load_par1(1);
    tap_addr(0, pdy0, pdx0, pm0);
    issue_half(0);
    issue_half(1);
    tap_addr(1, pdy1, pdx1, pm1);
    load_par0(2);
    issue_half(2);

    // weight staging visible to all waves; gathers stay in flight (lgkm only)
    asm volatile("s_waitcnt lgkmcnt(0)\n\ts_barrier" ::: "memory");

    f32x4 acc[8];
#pragma unroll
    for (int i = 0; i < 8; ++i) acc[i] = (f32x4){0.f, 0.f, 0.f, 0.f};

#pragma unroll
    for (int h = 0; h < 18; ++h) {
        const int k = h >> 1, p = h & 1;
        // issue side: at odd h, compute tap (h+3)/2's addresses + ping-pong refill
        if (h + 3 < 18) {
            if (((h + 3) & 1) == 0) {
                int kt = (h + 3) >> 1;            // k+2
                if (kt & 1) { tap_addr(kt, pdy1, pdx1, pm1); if (kt+1 < 9) load_par0(kt+1); }
                else        { tap_addr(kt, pdy0, pdx0, pm0); if (kt+1 < 9) load_par1(kt+1); }
            }
            issue_half(h + 3);
        }

        // consume half h: lerp -> one B fragment -> 8 MFMA
        const float* W = wts[k % 3];
        f16x8 bf = lerp8h(G[h & 3][0], G[h & 3][1], G[h & 3][2], G[h & 3][3],
                          splat8(W[0]), splat8(W[1]), splat8(W[2]), splat8(W[3]));
        const char* wb = (const char*)wlds + k*16384;
        const int lo = p ? lo1 : lo0;
#pragma unroll
        for (int mi = 0; mi < 8; ++mi) {
            u32x4 a = *(const u32x4*)(wb + (abase + lo + mi*2048));
            acc[mi] = __builtin_amdgcn_mfma_f32_16x16x32_f16(
                          __builtin_bit_cast(f16x8, a), bf, acc[mi], 0, 0, 0);
        }
    }

#pragma unroll
    for (int mi = 0; mi < 8; ++mi) {
#pragma unroll
        for (int r = 0; r < 4; ++r) {
            int o = mi*16 + hi*4 + r;     // C/D: col=lane&15(px), row=(lane>>4)*4+reg
            out[((b*CO + o)*HH + ho)*WW + wo] = acc[mi][r];
        }
    }
}

// ---------------------------------------------------------------------------
extern "C" void kernel_launch(void* const* d_in, const int* in_sizes, int n_in,
                              void* d_out, int out_size, void* d_ws, size_t ws_size,
                              hipStream_t stream) {
    const float* x  = (const float*)d_in[0];
    const float* ow = (const float*)d_in[1];
    const float* ob = (const float*)d_in[2];
    const float* wm = (const float*)d_in[3];
    float* outp = (float*)d_out;

    float* ws   = (float*)d_ws;
    unsigned int* xtb = (unsigned int*)(ws + XTB_OFF);
    unsigned short* owb = (unsigned short*)(ws + OWB_OFF);
    unsigned short* wtF = (unsigned short*)(ws + WTF_OFF);

    k_transpose_x<<<1024, 256, 0, stream>>>(x, xtb);
    k_prep_w<<<360, 256, 0, stream>>>(ow, wm, owb, wtF);
    k_fused<<<256, 1024, 0, stream>>>(xtb, owb, ob, wtF, outp);
}